// Round 7
// baseline (521.523 us; speedup 1.0000x reference)
//
#include <hip/hip_runtime.h>
#include <math.h>

// MoE gate: gate = inp[16384,2048]f32 @ W[64,2048]^T + b[64]; top-2; softmax.
// d_out (float32): [tokens*2] indices-as-floats, then [tokens*2] scores.
//
// Round 7: scalar-W delivery (R3-R6) is dead: per-k wall 1425cyc vs 128 FMA
// = serialized scalar-cache misses that occupancy can't hide. New structure:
// classic register-tiled GEMM, per-thread 16 tokens x 8 experts (128 FMAs
// per 6 ds_read_b128 -> ~1.4x LDS-bound, floor ~40us). A stored [k][C(t)]
// with a 4-float gap every 16 tokens -> conflict-free a-frag reads.
// waves_per_eu(2,2): the only config that allocated honestly (R5).

#define KDIM 2048
#define NEXP 64
#define BTOK 512          // tokens per block
#define BK   8            // k per LDS tile
#define AROW 640          // A-tile row stride in floats (C(511)=635 -> 640, %32==0)
#define WROW 68           // W-tile row stride (64+4)

__device__ __forceinline__ int cgap(int t) { return t + ((t >> 4) << 2); }

// ---------------- W transpose: W[64][2048] -> Wt[2048][64] ----------------
__global__ __launch_bounds__(256) void transpose_w_kernel(
    const float* __restrict__ W, float* __restrict__ Wt)
{
    const int idx = blockIdx.x * 256 + threadIdx.x;   // 131072 total
    const int e = idx >> 11;       // expert 0..63
    const int k = idx & 2047;      // k 0..2047
    Wt[k * NEXP + e] = W[idx];
}

// ---------------- GEMM partial: 16 tok x 8 exp per thread -----------------
__global__ __launch_bounds__(256)
__attribute__((amdgpu_waves_per_eu(2, 2)))
void gate_partial_kernel(
    const float* __restrict__ inp,
    const float* __restrict__ Wt,      // [KDIM][NEXP]
    float* __restrict__ partial,       // [S][tokens][NEXP]
    int tokens, int kPerSplit)
{
    __shared__ float As[BK * AROW];    // [k][C(token)]  20.0 KB
    __shared__ float Ws[BK * WROW];    // [k][expert]     2.2 KB

    const int tid     = threadIdx.x;
    const int tx      = tid & 7;       // expert group: 8*tx .. 8*tx+7
    const int tg      = tid >> 3;      // token group: 16*tg .. 16*tg+15
    const int tokBase = blockIdx.x * BTOK;
    const int split   = blockIdx.y;
    const int k0g     = split * kPerSplit;

    // A staging: 512 tok x 8 k per tile; thread covers t=(tid>>2)+64p (p<8),
    // k = (tid&3)*4 .. +3 as one float4. 4 lanes/row = 64B segments.
    const int st  = tid >> 2;           // 0..63
    const int sk  = (tid & 3) << 2;     // 0,4,8,12 -> but BK=8: use &1
    // BK=8 -> k-quads per row = 2; remap: t=(tid>>1)+128p? Keep 4 passes:
    // thread covers t=(tid>>1)+128p (p<4), k=(tid&1)*4..+3.
    const int st2 = tid >> 1;           // 0..127
    const int sk2 = (tid & 1) << 2;     // 0 or 4
    const float* aBase = inp + (size_t)tokBase * KDIM + k0g;

    // W staging: 8k x 64e = 512 floats; thread covers 2 (float2).
    const int wi = tid << 1;            // 0..510
    const int wk = wi >> 6;             // 0..7
    const int we = wi & 63;             // 0..62 even

    float4 stage[4];
    float2 wstage;
    #pragma unroll
    for (int p = 0; p < 4; ++p)
        stage[p] = *(const float4*)(aBase + (size_t)(st2 + 128 * p) * KDIM + sk2);
    wstage = *(const float2*)(Wt + (size_t)(k0g + wk) * NEXP + we);

    float acc[16][8];
    #pragma unroll
    for (int i = 0; i < 16; ++i)
        #pragma unroll
        for (int j = 0; j < 8; ++j) acc[i][j] = 0.0f;

    const int NT = kPerSplit / BK;     // 16 tiles for S=16
    const int ctg = tg * 20;           // C(tg*16)
    for (int kt = 0; kt < NT; ++kt) {
        __syncthreads();
        #pragma unroll
        for (int p = 0; p < 4; ++p) {
            const int t = st2 + 128 * p;
            const int ct = cgap(t);
            #pragma unroll
            for (int c = 0; c < 4; ++c)
                As[(sk2 + c) * AROW + ct] = ((const float*)&stage[p])[c];
        }
        *(float2*)&Ws[wk * WROW + we] = wstage;
        __syncthreads();
        if (kt + 1 < NT) {
            const int koff = (kt + 1) * BK;
            #pragma unroll
            for (int p = 0; p < 4; ++p)
                stage[p] = *(const float4*)(aBase + (size_t)(st2 + 128 * p) * KDIM + koff + sk2);
            wstage = *(const float2*)(Wt + (size_t)(k0g + koff + wk) * NEXP + we);
        }
        #pragma unroll
        for (int k = 0; k < BK; ++k) {
            float4 a0 = *(const float4*)&As[k * AROW + ctg];
            float4 a1 = *(const float4*)&As[k * AROW + ctg + 4];
            float4 a2 = *(const float4*)&As[k * AROW + ctg + 8];
            float4 a3 = *(const float4*)&As[k * AROW + ctg + 12];
            float4 w0 = *(const float4*)&Ws[k * WROW + tx * 8];
            float4 w1 = *(const float4*)&Ws[k * WROW + tx * 8 + 4];
            const float a[16] = { a0.x,a0.y,a0.z,a0.w, a1.x,a1.y,a1.z,a1.w,
                                  a2.x,a2.y,a2.z,a2.w, a3.x,a3.y,a3.z,a3.w };
            const float w[8]  = { w0.x,w0.y,w0.z,w0.w, w1.x,w1.y,w1.z,w1.w };
            #pragma unroll
            for (int i = 0; i < 16; ++i)
                #pragma unroll
                for (int j = 0; j < 8; ++j)
                    acc[i][j] = fmaf(a[i], w[j], acc[i][j]);
        }
    }

    // write partials: token tokBase+tg*16+i, experts tx*8..+7 (2 float4)
    #pragma unroll
    for (int i = 0; i < 16; ++i) {
        const int token = tokBase + tg * 16 + i;
        float* p = partial + ((size_t)split * tokens + token) * NEXP + tx * 8;
        *(float4*)&p[0] = make_float4(acc[i][0], acc[i][1], acc[i][2], acc[i][3]);
        *(float4*)&p[4] = make_float4(acc[i][4], acc[i][5], acc[i][6], acc[i][7]);
    }
}

// ---------------- reduce over splits + bias + top-2 + softmax -------------
__global__ __launch_bounds__(256) void reduce_topk_kernel(
    const float* __restrict__ partial,
    const float* __restrict__ bias,
    float* __restrict__ out,
    int tokens, int S)
{
    const int tid = threadIdx.x;
    const int tx  = tid & 15;          // experts 4*tx..4*tx+3
    const int ty  = tid >> 4;          // 16 tokens per block
    const int token = blockIdx.x * 16 + ty;
    const int eBase = tx << 2;

    float4 v = make_float4(0.f, 0.f, 0.f, 0.f);
    for (int s = 0; s < S; ++s) {
        const float4 p = *(const float4*)&partial[((size_t)s * tokens + token) * NEXP + eBase];
        v.x += p.x; v.y += p.y; v.z += p.z; v.w += p.w;
    }
    const float4 bv = *(const float4*)&bias[eBase];
    float g[4] = { v.x + bv.x, v.y + bv.y, v.z + bv.z, v.w + bv.w };

    // local top-2 (ascending scan keeps lower index on ties, matching lax.top_k)
    float v1 = g[0]; int i1 = eBase;
    float v2 = -INFINITY; int i2 = -1;
    #pragma unroll
    for (int c = 1; c < 4; ++c) {
        const float vv = g[c];
        const int   ii = eBase + c;
        if (vv > v1)      { v2 = v1; i2 = i1; v1 = vv; i1 = ii; }
        else if (vv > v2) { v2 = vv; i2 = ii; }
    }
    // 16-lane butterfly merge
    #pragma unroll
    for (int m = 1; m <= 8; m <<= 1) {
        const float ov1 = __shfl_xor(v1, m);
        const int   oi1 = __shfl_xor(i1, m);
        const float ov2 = __shfl_xor(v2, m);
        const int   oi2 = __shfl_xor(i2, m);
        const bool aw = (v1 > ov1) || (v1 == ov1 && i1 < oi1);
        const float nv1 = aw ? v1  : ov1;  const int ni1 = aw ? i1  : oi1;
        const float lv  = aw ? ov1 : v1;   const int li  = aw ? oi1 : i1;
        const float sv  = aw ? v2  : ov2;  const int si  = aw ? i2  : oi2;
        const bool sw = (sv > lv) || (sv == lv && si < li);
        v1 = nv1; i1 = ni1;
        v2 = sw ? sv : lv; i2 = sw ? si : li;
    }
    if (tx == 0) {
        const float e2 = expf(v2 - v1);
        const float denom = 1.0f + e2;
        out[2 * token]     = (float)i1;
        out[2 * token + 1] = (float)i2;
        out[tokens * 2 + 2 * token]     = 1.0f / denom;
        out[tokens * 2 + 2 * token + 1] = e2 / denom;
    }
}

extern "C" void kernel_launch(void* const* d_in, const int* in_sizes, int n_in,
                              void* d_out, int out_size, void* d_ws, size_t ws_size,
                              hipStream_t stream) {
    const float* inp  = (const float*)d_in[0];
    const float* W    = (const float*)d_in[1];
    const float* bias = (const float*)d_in[2];
    float* out = (float*)d_out;

    const int tokens = in_sizes[0] / KDIM;   // 16384

    // S=16 -> grid 32x16=512 blocks (2/CU). Fall back if ws too small.
    int S = 16;
    while (S > 1 &&
           (size_t)S * tokens * NEXP * sizeof(float) + (size_t)KDIM * NEXP * sizeof(float) > ws_size)
        S >>= 1;
    const int kPerSplit = KDIM / S;

    float* partial = (float*)d_ws;
    float* Wt = partial + (size_t)S * tokens * NEXP;

    transpose_w_kernel<<<(NEXP * KDIM) / 256, 256, 0, stream>>>(W, Wt);

    dim3 grid(tokens / BTOK, S);
    gate_partial_kernel<<<grid, 256, 0, stream>>>(inp, Wt, partial, tokens, kPerSplit);

    reduce_topk_kernel<<<tokens / 16, 256, 0, stream>>>(partial, bias, out, tokens, S);
}